// Round 14
// baseline (75.038 us; speedup 1.0000x reference)
//
#include <hip/hip_runtime.h>
#include <math.h>

#define W 512
#define H 512
#define NUM_R 725
#define NUM_T 180
#define RCHUNK 128              // sweep-rows per block; grid (180,4) = 720 blocks
#define NCHUNK (H / RCHUNK)     // 4
#define RPAD 768                // padded rho bins

// ws layout: [0, W*H) floats = imgT ; then NCHUNK*NUM_T*RPAD floats = partials
#define WS_FLOATS ((size_t)W * H + (size_t)NCHUNK * NUM_T * RPAD)

// ---------------------------------------------------------------------------
// Transpose 512x512 f32: imgT[a*H + b] = img[b*W + a]
// ---------------------------------------------------------------------------
__global__ __launch_bounds__(256) void transpose_k(const float* __restrict__ in,
                                                   float* __restrict__ out) {
    __shared__ float tile[32][33];
    const int bx = blockIdx.x * 32, by = blockIdx.y * 32;
    const int tx = threadIdx.x, ty = threadIdx.y;  // block (32, 8)
#pragma unroll
    for (int j = 0; j < 32; j += 8)
        tile[ty + j][tx] = in[(size_t)(by + ty + j) * W + (bx + tx)];
    __syncthreads();
#pragma unroll
    for (int j = 0; j < 32; j += 8)
        out[(size_t)(bx + ty + j) * H + (by + tx)] = tile[tx][ty + j];
}

// ---------------------------------------------------------------------------
// Run-batched inner loop: 16 consecutive rows, flush every P rows.
// Invariant (guaranteed by P selection: lane_a + (P-1)*loop_a < 0.98):
// within a P-row window, all hits (frac(u) <= B) lie in ONE bin = hi32(u) at
// the window's last row. Zero-acc flushes land on a valid bin (harmless).
// u advances by +lqa every row (rows walked in reverse when loop_co < 0).
// (Validated R11/R13: absmax 2.0.)
// ---------------------------------------------------------------------------
template <int P>
__device__ __forceinline__ void run16(const float4* __restrict__ rp, int rstep,
                                      long long u, long long lqa,
                                      long long L1, long long L2, long long L3,
                                      unsigned B, float* __restrict__ racc_w) {
#pragma unroll
    for (int per = 0; per < 16 / P; ++per) {
        float a0 = 0.f, a1 = 0.f, a2 = 0.f, a3 = 0.f;
        long long u0 = 0, u1 = 0, u2 = 0, u3 = 0;
#pragma unroll
        for (int p = 0; p < P; ++p) {
            const float4 v = rp[(per * P + p) * rstep];
            u0 = u; u1 = u + L1; u2 = u + L2; u3 = u + L3;
            a0 += ((unsigned)u0 <= B) ? v.x : 0.f;
            a1 += ((unsigned)u1 <= B) ? v.y : 0.f;
            a2 += ((unsigned)u2 <= B) ? v.z : 0.f;
            a3 += ((unsigned)u3 <= B) ? v.w : 0.f;
            if (p < P - 1) u += lqa;
        }
        // one RMW pair per slot per P rows (same-thread in-order; lane bins
        // distinct: slot spacing 4*lane_a >= 1.38 bins; wave-private racc)
        racc_w[(int)(u0 >> 32)] += a0;
        racc_w[(int)(u1 >> 32)] += a1;
        racc_w[(int)(u2 >> 32)] += a2;
        racc_w[(int)(u3 >> 32)] += a3;
        u += lqa;
    }
}

// ---------------------------------------------------------------------------
// Scatter Hough. Session rules: NO fp atomics (R4/R5/R8: any fp32 atomic path
// ~100us), NO device-scope fences (R9: ~100us), NO theta-pairing (R12: fatter
// inner loop regressed). R14 = R13 inner loop, RCHUNK 128: each thread runs
// run16 four times (four 16-row groups) -> per-block zero/flush fixed costs
// and reduce_k input amortized 2x again; 720 blocks = 2.8/CU = 11 waves/CU
// (streaming kernel, MLP is per-thread via 16 unrolled independent loads).
// Hit math (validated absmax 2.0 since R10): pixel hits bin r iff
// frac(u + hwq-bias) <= 2*hwq, bin = hi32(u); u Q32, f64-refreshed per group.
// Thread layout: threads 0-127 -> rows [n0, n0+64), threads 128-255 ->
// rows [n0+64, n0+128); 4 consecutive columns per thread (float4 loads).
// ---------------------------------------------------------------------------
__global__ __launch_bounds__(256) void hough_scatter_k(const float* __restrict__ img,
                                                       const float* __restrict__ imgT,
                                                       float* __restrict__ partial) {
    const int t   = blockIdx.x;            // theta 0..179
    const int n0  = blockIdx.y * RCHUNK;   // sweep-row chunk base
    const int tid = threadIdx.x;
    const int wave = tid >> 6;

    __shared__ float racc[4 * RPAD];       // per-wave private accumulators (12 KB)

    {   // zero accumulators (768 float4)
        float4* z = (float4*)racc;
#pragma unroll
        for (int k = 0; k < 3; ++k)
            z[tid + 256 * k] = make_float4(0.f, 0.f, 0.f, 0.f);
    }
    __syncthreads();

    // ---- per-theta constants (f64, same trig path validated R1-R13) ----
    const double theta = (double)t * (M_PI / 180.0);
    const double s = sin(theta);
    const double c = cos(theta);
    const bool use_x = fabs(s) >= fabs(c);
    const double diag = sqrt(524288.0);          // sqrt(W*W + H*H)
    const double step = (2.0 * diag) / 724.0;    // np.linspace step
    const double inv_step = 1.0 / step;

    const double lane_co = (use_x ? s : c) * inv_step;  // du per pixel (lane axis)
    const double loop_co = (use_x ? c : s) * inv_step;  // du per sweep row
    const double dstep   = diag * inv_step;
    const double lane_a  = fabs(lane_co);               // in [0.345, 0.5)
    const double loop_a  = fabs(loop_co);               // in [0, 0.354]

    const double SC = 4294967296.0;              // 2^32
    const long long laneq = (long long)rint(lane_co * SC);   // signed
    const long long lqa   = llabs((long long)rint(loop_co * SC));
    const long long L1 = laneq, L2 = 2 * laneq, L3 = 3 * laneq;
    const unsigned hwq = (unsigned)(lane_a * 0.5 * SC);
    const unsigned B = 2u * hwq;                 // hit iff lo32(u) <= B

    // ---- P selection: largest P in {16,8,4,2} with lane_a+(P-1)*loop_a<0.98
    int P = 2;
    if      (lane_a + 15.0 * loop_a < 0.98) P = 16;
    else if (lane_a +  7.0 * loop_a < 0.98) P = 8;
    else if (lane_a +  3.0 * loop_a < 0.98) P = 4;

    // ---- thread mapping: 64 consecutive rows (four 16-row groups) ----
    const int h  = tid >> 7;                     // row-half within block
    const int c0 = (tid & 127) * 4;              // column base
    const bool neg = (loop_co < 0.0);
    const int rstep  = neg ? -(W / 4) : (W / 4); // float4 units

    float* racc_w = racc + wave * RPAD;
    const float* __restrict__ base = use_x ? img : imgT;

#pragma unroll
    for (int g = 0; g < 4; ++g) {
        const int rbase = n0 + 64 * h + 16 * g;
        const int rstart = neg ? rbase + 15 : rbase;   // walk rows so u increases
        const long long u =
            (long long)rint(((double)rstart * loop_co +
                             (double)c0 * lane_co + dstep) * SC)
            + (long long)hwq;
        const float4* rp = (const float4*)base + (size_t)rstart * (W / 4) + (tid & 127);

        switch (P) {
            case 16: run16<16>(rp, rstep, u, lqa, L1, L2, L3, B, racc_w); break;
            case 8:  run16<8> (rp, rstep, u, lqa, L1, L2, L3, B, racc_w); break;
            case 4:  run16<4> (rp, rstep, u, lqa, L1, L2, L3, B, racc_w); break;
            default: run16<2> (rp, rstep, u, lqa, L1, L2, L3, B, racc_w); break;
        }
    }

    __syncthreads();

    // ---- non-atomic flush: partial[chunk][t][r] (coalesced) ----
    float* dst = partial + ((size_t)blockIdx.y * NUM_T + t) * RPAD;
#pragma unroll
    for (int k = 0; k < 3; ++k) {
        const int r = tid + 256 * k;
        dst[r] = racc[r] + racc[RPAD + r] + racc[2 * RPAD + r] + racc[3 * RPAD + r];
    }
}

// ---------------------------------------------------------------------------
// Sum the NCHUNK partials into out[r*NUM_T + t]. Block = one theta.
// ---------------------------------------------------------------------------
__global__ __launch_bounds__(256) void reduce_k(const float* __restrict__ partial,
                                                float* __restrict__ out) {
    const int t = blockIdx.x;
    const int tid = threadIdx.x;
#pragma unroll
    for (int k = 0; k < 3; ++k) {
        const int r = tid + 256 * k;
        if (r < NUM_R) {
            float acc = 0.f;
#pragma unroll
            for (int ch = 0; ch < NCHUNK; ++ch)
                acc += partial[((size_t)ch * NUM_T + t) * RPAD + r];
            out[(size_t)r * NUM_T + t] = acc;
        }
    }
}

// ---------------------------------------------------------------------------
// Fallback (ws too small): R3's pure-gather kernel, no ws, no atomics.
// ---------------------------------------------------------------------------
__global__ __launch_bounds__(256) void hough_gather_k(const float* __restrict__ img,
                                                      float* __restrict__ out) {
    const int t = blockIdx.x;
    const int r = blockIdx.y * 256 + threadIdx.x;
    const int rc = (r < NUM_R) ? r : (NUM_R - 1);

    const double theta = (double)t * (M_PI / 180.0);
    const double s = sin(theta);
    const double c = cos(theta);
    const bool use_x = fabs(s) >= fabs(c);
    double dd = use_x ? s : c;
    if (fabs(dd) < 1e-6) dd = 1.0;
    const double a = use_x ? c : s;
    const double inv = 1.0 / dd;
    const double nk2 = -(a * inv);
    const double diag = sqrt(524288.0);
    const double step = (2.0 * diag) / 724.0;
    double rho = (double)rc * step - diag;
    if (rc == NUM_R - 1) rho = diag;

    const double SCALE = 1099511627776.0;  // 2^40
    const long long NK2q = (long long)rint(nk2 * SCALE);
    long long Y = (long long)rint(rho * inv * SCALE) + (1ll << 39);

    float acc = 0.f;
    if (use_x) {
#pragma unroll 8
        for (int n = 0; n < W; ++n) {
            const int y = (int)(Y >> 40);
            Y += NK2q;
            const float v = img[n * W + min(max(y, 0), W - 1)];
            acc += ((unsigned)y < (unsigned)W) ? v : 0.f;
        }
    } else {
#pragma unroll 4
        for (int n = 0; n < W; ++n) {
            const int y = (int)(Y >> 40);
            Y += NK2q;
            const float v = img[min(max(y, 0), W - 1) * W + n];
            acc += ((unsigned)y < (unsigned)W) ? v : 0.f;
        }
    }
    if (r < NUM_R) out[(size_t)r * NUM_T + t] = acc;
}

extern "C" void kernel_launch(void* const* d_in, const int* in_sizes, int n_in,
                              void* d_out, int out_size, void* d_ws, size_t ws_size,
                              hipStream_t stream) {
    const float* img = (const float*)d_in[0];
    float* out = (float*)d_out;

    if (ws_size >= WS_FLOATS * sizeof(float)) {
        float* imgT    = (float*)d_ws;
        float* partial = (float*)d_ws + (size_t)W * H;

        transpose_k<<<dim3(16, 16), dim3(32, 8), 0, stream>>>(img, imgT);
        hough_scatter_k<<<dim3(NUM_T, NCHUNK), dim3(256), 0, stream>>>(img, imgT, partial);
        reduce_k<<<dim3(NUM_T), dim3(256), 0, stream>>>(partial, out);
    } else {
        hough_gather_k<<<dim3(NUM_T, (NUM_R + 255) / 256), dim3(256), 0, stream>>>(img, out);
    }
}

// Round 15
// 71.610 us; speedup vs baseline: 1.0479x; 1.0479x over previous
//
#include <hip/hip_runtime.h>
#include <math.h>

#define W 512
#define H 512
#define NUM_R 725
#define NUM_T 180
#define RCHUNK 64               // sweep-rows per block; grid (180,8) = 1440 blocks
#define NCHUNK (H / RCHUNK)     // 8
#define RPAD 768                // padded rho bins

// ws layout: [0, W*H) floats = imgT ; then NCHUNK*NUM_T*RPAD floats = partials
#define WS_FLOATS ((size_t)W * H + (size_t)NCHUNK * NUM_T * RPAD)

// ---------------------------------------------------------------------------
// Transpose 512x512 f32: imgT[a*H + b] = img[b*W + a]
// ---------------------------------------------------------------------------
__global__ __launch_bounds__(256) void transpose_k(const float* __restrict__ in,
                                                   float* __restrict__ out) {
    __shared__ float tile[32][33];
    const int bx = blockIdx.x * 32, by = blockIdx.y * 32;
    const int tx = threadIdx.x, ty = threadIdx.y;  // block (32, 8)
#pragma unroll
    for (int j = 0; j < 32; j += 8)
        tile[ty + j][tx] = in[(size_t)(by + ty + j) * W + (bx + tx)];
    __syncthreads();
#pragma unroll
    for (int j = 0; j < 32; j += 8)
        out[(size_t)(bx + ty + j) * H + (by + tx)] = tile[tx][ty + j];
}

// ---------------------------------------------------------------------------
// Run-batched inner loop: 16 consecutive rows, flush every P rows.
// Invariant (guaranteed by P selection: lane_a + (P-1)*loop_a < 0.98):
// within a P-row window, all hits (frac(u) <= B) lie in ONE bin = hi32(u) at
// the window's last row. Zero-acc flushes land on a valid bin (harmless).
// u advances by +lqa every row (rows walked in reverse when loop_co < 0).
// (Validated R11/R13: absmax 2.0, wall 72.1 at RCHUNK 64.)
// ---------------------------------------------------------------------------
template <int P>
__device__ __forceinline__ void run16(const float4* __restrict__ rp, int rstep,
                                      long long u, long long lqa,
                                      long long L1, long long L2, long long L3,
                                      unsigned B, float* __restrict__ racc_w) {
#pragma unroll
    for (int per = 0; per < 16 / P; ++per) {
        float a0 = 0.f, a1 = 0.f, a2 = 0.f, a3 = 0.f;
        long long u0 = 0, u1 = 0, u2 = 0, u3 = 0;
#pragma unroll
        for (int p = 0; p < P; ++p) {
            const float4 v = rp[(per * P + p) * rstep];
            u0 = u; u1 = u + L1; u2 = u + L2; u3 = u + L3;
            a0 += ((unsigned)u0 <= B) ? v.x : 0.f;
            a1 += ((unsigned)u1 <= B) ? v.y : 0.f;
            a2 += ((unsigned)u2 <= B) ? v.z : 0.f;
            a3 += ((unsigned)u3 <= B) ? v.w : 0.f;
            if (p < P - 1) u += lqa;
        }
        // one RMW pair per slot per P rows (same-thread in-order; lane bins
        // distinct: slot spacing 4*lane_a >= 1.38 bins; wave-private racc)
        racc_w[(int)(u0 >> 32)] += a0;
        racc_w[(int)(u1 >> 32)] += a1;
        racc_w[(int)(u2 >> 32)] += a2;
        racc_w[(int)(u3 >> 32)] += a3;
        u += lqa;
    }
}

// ---------------------------------------------------------------------------
// Scatter Hough — R13 configuration (session best: 72.1 us).
// Session rules (all measured): NO fp atomics (R4/R5/R8: any fp32 atomic
// path ~100us), NO device-scope fences (R9: ~100us), NO theta-pairing (R12
// regressed), RCHUNK 64 optimal (32: R11 73.0; 64: R13 72.1; 128: R14 75.0).
// Hit math (validated absmax 2.0 since R10): pixel hits bin r iff
// frac(u + hwq-bias) <= 2*hwq, bin = hi32(u); u Q32, f64-refreshed per group.
// Thread layout: threads 0-127 -> rows [n0, n0+32), threads 128-255 ->
// rows [n0+32, n0+64); 4 consecutive columns per thread (float4 loads).
// ---------------------------------------------------------------------------
__global__ __launch_bounds__(256) void hough_scatter_k(const float* __restrict__ img,
                                                       const float* __restrict__ imgT,
                                                       float* __restrict__ partial) {
    const int t   = blockIdx.x;            // theta 0..179
    const int n0  = blockIdx.y * RCHUNK;   // sweep-row chunk base
    const int tid = threadIdx.x;
    const int wave = tid >> 6;

    __shared__ float racc[4 * RPAD];       // per-wave private accumulators (12 KB)

    {   // zero accumulators (768 float4)
        float4* z = (float4*)racc;
#pragma unroll
        for (int k = 0; k < 3; ++k)
            z[tid + 256 * k] = make_float4(0.f, 0.f, 0.f, 0.f);
    }
    __syncthreads();

    // ---- per-theta constants (f64, same trig path validated R1-R14) ----
    const double theta = (double)t * (M_PI / 180.0);
    const double s = sin(theta);
    const double c = cos(theta);
    const bool use_x = fabs(s) >= fabs(c);
    const double diag = sqrt(524288.0);          // sqrt(W*W + H*H)
    const double step = (2.0 * diag) / 724.0;    // np.linspace step
    const double inv_step = 1.0 / step;

    const double lane_co = (use_x ? s : c) * inv_step;  // du per pixel (lane axis)
    const double loop_co = (use_x ? c : s) * inv_step;  // du per sweep row
    const double dstep   = diag * inv_step;
    const double lane_a  = fabs(lane_co);               // in [0.345, 0.5)
    const double loop_a  = fabs(loop_co);               // in [0, 0.354]

    const double SC = 4294967296.0;              // 2^32
    const long long laneq = (long long)rint(lane_co * SC);   // signed
    const long long lqa   = llabs((long long)rint(loop_co * SC));
    const long long L1 = laneq, L2 = 2 * laneq, L3 = 3 * laneq;
    const unsigned hwq = (unsigned)(lane_a * 0.5 * SC);
    const unsigned B = 2u * hwq;                 // hit iff lo32(u) <= B

    // ---- P selection: largest P in {16,8,4,2} with lane_a+(P-1)*loop_a<0.98
    int P = 2;
    if      (lane_a + 15.0 * loop_a < 0.98) P = 16;
    else if (lane_a +  7.0 * loop_a < 0.98) P = 8;
    else if (lane_a +  3.0 * loop_a < 0.98) P = 4;

    // ---- thread mapping: 32 consecutive rows (two 16-row groups) ----
    const int h  = tid >> 7;                     // row-half within block
    const int c0 = (tid & 127) * 4;              // column base
    const bool neg = (loop_co < 0.0);
    const int rstep  = neg ? -(W / 4) : (W / 4); // float4 units

    float* racc_w = racc + wave * RPAD;
    const float* __restrict__ base = use_x ? img : imgT;

#pragma unroll
    for (int g = 0; g < 2; ++g) {
        const int rbase = n0 + 32 * h + 16 * g;
        const int rstart = neg ? rbase + 15 : rbase;   // walk rows so u increases
        const long long u =
            (long long)rint(((double)rstart * loop_co +
                             (double)c0 * lane_co + dstep) * SC)
            + (long long)hwq;
        const float4* rp = (const float4*)base + (size_t)rstart * (W / 4) + (tid & 127);

        switch (P) {
            case 16: run16<16>(rp, rstep, u, lqa, L1, L2, L3, B, racc_w); break;
            case 8:  run16<8> (rp, rstep, u, lqa, L1, L2, L3, B, racc_w); break;
            case 4:  run16<4> (rp, rstep, u, lqa, L1, L2, L3, B, racc_w); break;
            default: run16<2> (rp, rstep, u, lqa, L1, L2, L3, B, racc_w); break;
        }
    }

    __syncthreads();

    // ---- non-atomic flush: partial[chunk][t][r] (coalesced) ----
    float* dst = partial + ((size_t)blockIdx.y * NUM_T + t) * RPAD;
#pragma unroll
    for (int k = 0; k < 3; ++k) {
        const int r = tid + 256 * k;
        dst[r] = racc[r] + racc[RPAD + r] + racc[2 * RPAD + r] + racc[3 * RPAD + r];
    }
}

// ---------------------------------------------------------------------------
// Sum the NCHUNK partials into out[r*NUM_T + t]. Block = one theta.
// ---------------------------------------------------------------------------
__global__ __launch_bounds__(256) void reduce_k(const float* __restrict__ partial,
                                                float* __restrict__ out) {
    const int t = blockIdx.x;
    const int tid = threadIdx.x;
#pragma unroll
    for (int k = 0; k < 3; ++k) {
        const int r = tid + 256 * k;
        if (r < NUM_R) {
            float acc = 0.f;
#pragma unroll
            for (int ch = 0; ch < NCHUNK; ++ch)
                acc += partial[((size_t)ch * NUM_T + t) * RPAD + r];
            out[(size_t)r * NUM_T + t] = acc;
        }
    }
}

// ---------------------------------------------------------------------------
// Fallback (ws too small): R3's pure-gather kernel, no ws, no atomics.
// ---------------------------------------------------------------------------
__global__ __launch_bounds__(256) void hough_gather_k(const float* __restrict__ img,
                                                      float* __restrict__ out) {
    const int t = blockIdx.x;
    const int r = blockIdx.y * 256 + threadIdx.x;
    const int rc = (r < NUM_R) ? r : (NUM_R - 1);

    const double theta = (double)t * (M_PI / 180.0);
    const double s = sin(theta);
    const double c = cos(theta);
    const bool use_x = fabs(s) >= fabs(c);
    double dd = use_x ? s : c;
    if (fabs(dd) < 1e-6) dd = 1.0;
    const double a = use_x ? c : s;
    const double inv = 1.0 / dd;
    const double nk2 = -(a * inv);
    const double diag = sqrt(524288.0);
    const double step = (2.0 * diag) / 724.0;
    double rho = (double)rc * step - diag;
    if (rc == NUM_R - 1) rho = diag;

    const double SCALE = 1099511627776.0;  // 2^40
    const long long NK2q = (long long)rint(nk2 * SCALE);
    long long Y = (long long)rint(rho * inv * SCALE) + (1ll << 39);

    float acc = 0.f;
    if (use_x) {
#pragma unroll 8
        for (int n = 0; n < W; ++n) {
            const int y = (int)(Y >> 40);
            Y += NK2q;
            const float v = img[n * W + min(max(y, 0), W - 1)];
            acc += ((unsigned)y < (unsigned)W) ? v : 0.f;
        }
    } else {
#pragma unroll 4
        for (int n = 0; n < W; ++n) {
            const int y = (int)(Y >> 40);
            Y += NK2q;
            const float v = img[min(max(y, 0), W - 1) * W + n];
            acc += ((unsigned)y < (unsigned)W) ? v : 0.f;
        }
    }
    if (r < NUM_R) out[(size_t)r * NUM_T + t] = acc;
}

extern "C" void kernel_launch(void* const* d_in, const int* in_sizes, int n_in,
                              void* d_out, int out_size, void* d_ws, size_t ws_size,
                              hipStream_t stream) {
    const float* img = (const float*)d_in[0];
    float* out = (float*)d_out;

    if (ws_size >= WS_FLOATS * sizeof(float)) {
        float* imgT    = (float*)d_ws;
        float* partial = (float*)d_ws + (size_t)W * H;

        transpose_k<<<dim3(16, 16), dim3(32, 8), 0, stream>>>(img, imgT);
        hough_scatter_k<<<dim3(NUM_T, NCHUNK), dim3(256), 0, stream>>>(img, imgT, partial);
        reduce_k<<<dim3(NUM_T), dim3(256), 0, stream>>>(partial, out);
    } else {
        hough_gather_k<<<dim3(NUM_T, (NUM_R + 255) / 256), dim3(256), 0, stream>>>(img, out);
    }
}